// Round 6
// baseline (625.607 us; speedup 1.0000x reference)
//
#include <hip/hip_runtime.h>
#include <hip/hip_bf16.h>

#define H 256
#define NTHREADS 256

// ---------- helpers ----------
static __device__ __forceinline__ float bf2f(unsigned short u) {
    return __uint_as_float(((unsigned int)u) << 16);
}
static __device__ __forceinline__ unsigned short f2bf(float f) {
    unsigned int x = __float_as_uint(f);
    unsigned int r = (x + 0x7fffu + ((x >> 16) & 1u)) >> 16;
    return (unsigned short)r;
}

typedef unsigned short us8 __attribute__((ext_vector_type(8)));
typedef __bf16 bf16x8 __attribute__((ext_vector_type(8)));
typedef float f32x4 __attribute__((ext_vector_type(4)));

// ---------- cast x (f32 -> bf16) into right half of Acat[m][512] ----------
__global__ __launch_bounds__(NTHREADS) void cast_x_kernel(
    const float* __restrict__ x, unsigned short* __restrict__ A, int n4)
{
    int i = blockIdx.x * NTHREADS + threadIdx.x;
    if (i < n4) {
        float4 v = ((const float4*)x)[i];
        ushort4 o;
        o.x = f2bf(v.x); o.y = f2bf(v.y); o.z = f2bf(v.z); o.w = f2bf(v.w);
        int m = i >> 6;          // 64 float4 per 256-col row
        int c = i & 63;
        ((ushort4*)(A + (size_t)m * 512 + H))[c] = o;
    }
}

// ---------- build Bcat[l][n][k] for all 3 layers in one launch ----------
// n in [0,256), k in [0,512): k<256 -> Wl[n][k], else Wr[n][k-256]
__global__ __launch_bounds__(NTHREADS) void cast_w_kernel(
    const float* __restrict__ Wl1, const float* __restrict__ Wr1,
    const float* __restrict__ Wl2, const float* __restrict__ Wr2,
    const float* __restrict__ Wl3, const float* __restrict__ Wr3,
    unsigned short* __restrict__ Bcat)
{
    int i = blockIdx.x * NTHREADS + threadIdx.x;   // 3*256*512 elements
    int l = i >> 17;
    int r = i & 131071;
    int n = r >> 9;
    int k = r & 511;
    const float* Wl = (l == 0) ? Wl1 : (l == 1) ? Wl2 : Wl3;
    const float* Wr = (l == 0) ? Wr1 : (l == 1) ? Wr2 : Wr3;
    float v = (k < H) ? Wl[n * H + k] : Wr[n * H + (k - H)];
    Bcat[i] = f2bf(v);
}

// ---------- degree histogram ----------
__global__ __launch_bounds__(NTHREADS) void hist_kernel(
    const int* __restrict__ dst, int* __restrict__ cnt, int E)
{
    int i = blockIdx.x * NTHREADS + threadIdx.x;
    if (i < E) atomicAdd(&cnt[dst[i]], 1);
}

// ---------- multi-block exclusive scan, stage 1 ----------
__global__ __launch_bounds__(NTHREADS) void scan_partial_kernel(
    const int* __restrict__ cnt, int* __restrict__ row_ptr,
    int* __restrict__ blocksum, int n_nodes)
{
    __shared__ int tmp[NTHREADS];
    int t = threadIdx.x;
    int i = blockIdx.x * NTHREADS + t;
    int v = (i < n_nodes) ? cnt[i] : 0;
    tmp[t] = v;
    __syncthreads();
#pragma unroll
    for (int d = 1; d < NTHREADS; d <<= 1) {
        int add = (t >= d) ? tmp[t - d] : 0;
        __syncthreads();
        tmp[t] += add;
        __syncthreads();
    }
    if (i < n_nodes) row_ptr[i] = tmp[t] - v;   // exclusive
    if (t == NTHREADS - 1) blocksum[blockIdx.x] = tmp[t];
}

// ---------- stage 2 ----------
__global__ __launch_bounds__(NTHREADS) void scan_sums_kernel(
    int* __restrict__ blocksum, int* __restrict__ blockoff,
    int* __restrict__ row_ptr, int n_blocks, int n_nodes)
{
    __shared__ int tmp[NTHREADS];
    int t = threadIdx.x;
    int v = (t < n_blocks) ? blocksum[t] : 0;
    tmp[t] = v;
    __syncthreads();
#pragma unroll
    for (int d = 1; d < NTHREADS; d <<= 1) {
        int add = (t >= d) ? tmp[t - d] : 0;
        __syncthreads();
        tmp[t] += add;
        __syncthreads();
    }
    if (t < n_blocks) blockoff[t] = tmp[t] - v;
    if (t == NTHREADS - 1) row_ptr[n_nodes] = tmp[t];
}

// ---------- stage 3 ----------
__global__ __launch_bounds__(NTHREADS) void scan_finish_kernel(
    const int* __restrict__ cnt, int* __restrict__ row_ptr,
    int* __restrict__ cursor, float* __restrict__ deg_inv,
    const int* __restrict__ blockoff, int n_nodes)
{
    int i = blockIdx.x * NTHREADS + threadIdx.x;
    if (i < n_nodes) {
        int r = row_ptr[i] + blockoff[blockIdx.x];
        row_ptr[i] = r;
        cursor[i] = r;
        deg_inv[i] = 1.0f / (float)max(cnt[i], 1);
    }
}

// ---------- scatter edges into CSR order ----------
__global__ __launch_bounds__(NTHREADS) void fill_kernel(
    const int* __restrict__ src, const int* __restrict__ dst,
    int* __restrict__ cursor, int* __restrict__ csr_src, int E)
{
    int i = blockIdx.x * NTHREADS + threadIdx.x;
    if (i < E) {
        int p = atomicAdd(&cursor[dst[i]], 1);
        csr_src[p] = src[i];
    }
}

// ---------- mean-aggregate: gather h rows (right half of Acat) -> agg (left half) ----------
// One wave per node. Lanes 0-31 even edges, 32-63 odd edges; 8 feats (16B) per lane.
__global__ __launch_bounds__(NTHREADS) void agg_kernel(
    const unsigned short* __restrict__ hsrc,   // Acat + 256 (h base), row stride 512
    unsigned short* __restrict__ aggdst,       // Acat (agg base), row stride 512
    const int* __restrict__ row_ptr, const int* __restrict__ csr_src,
    const float* __restrict__ deg_inv, int n_nodes)
{
    int wave = threadIdx.x >> 6;
    int lane = threadIdx.x & 63;
    int node = blockIdx.x * 4 + wave;
    if (node >= n_nodes) return;
    int beg = row_ptr[node];
    int cnt = row_ptr[node + 1] - beg;
    const int half = lane >> 5;
    const int foff = (lane & 31) * 8;
    const unsigned short* hb = hsrc + foff;

    float a[8] = {0.f, 0.f, 0.f, 0.f, 0.f, 0.f, 0.f, 0.f};

    for (int e = 0; e < cnt; e += 64) {
        int rem = min(64, cnt - e);
        int idx = (lane < rem) ? csr_src[beg + e + lane] : 0;
        int j = 0;
        for (; j + 16 <= rem; j += 16) {
            int s0 = __shfl(idx, j + 0 + half);
            int s1 = __shfl(idx, j + 2 + half);
            int s2 = __shfl(idx, j + 4 + half);
            int s3 = __shfl(idx, j + 6 + half);
            int s4 = __shfl(idx, j + 8 + half);
            int s5 = __shfl(idx, j + 10 + half);
            int s6 = __shfl(idx, j + 12 + half);
            int s7 = __shfl(idx, j + 14 + half);
            us8 v0 = *(const us8*)(hb + ((size_t)s0 << 9));
            us8 v1 = *(const us8*)(hb + ((size_t)s1 << 9));
            us8 v2 = *(const us8*)(hb + ((size_t)s2 << 9));
            us8 v3 = *(const us8*)(hb + ((size_t)s3 << 9));
            us8 v4 = *(const us8*)(hb + ((size_t)s4 << 9));
            us8 v5 = *(const us8*)(hb + ((size_t)s5 << 9));
            us8 v6 = *(const us8*)(hb + ((size_t)s6 << 9));
            us8 v7 = *(const us8*)(hb + ((size_t)s7 << 9));
#pragma unroll
            for (int t = 0; t < 8; ++t) a[t] += bf2f(v0[t]);
#pragma unroll
            for (int t = 0; t < 8; ++t) a[t] += bf2f(v1[t]);
#pragma unroll
            for (int t = 0; t < 8; ++t) a[t] += bf2f(v2[t]);
#pragma unroll
            for (int t = 0; t < 8; ++t) a[t] += bf2f(v3[t]);
#pragma unroll
            for (int t = 0; t < 8; ++t) a[t] += bf2f(v4[t]);
#pragma unroll
            for (int t = 0; t < 8; ++t) a[t] += bf2f(v5[t]);
#pragma unroll
            for (int t = 0; t < 8; ++t) a[t] += bf2f(v6[t]);
#pragma unroll
            for (int t = 0; t < 8; ++t) a[t] += bf2f(v7[t]);
        }
        for (; j + 8 <= rem; j += 8) {
            int s0 = __shfl(idx, j + 0 + half);
            int s1 = __shfl(idx, j + 2 + half);
            int s2 = __shfl(idx, j + 4 + half);
            int s3 = __shfl(idx, j + 6 + half);
            us8 v0 = *(const us8*)(hb + ((size_t)s0 << 9));
            us8 v1 = *(const us8*)(hb + ((size_t)s1 << 9));
            us8 v2 = *(const us8*)(hb + ((size_t)s2 << 9));
            us8 v3 = *(const us8*)(hb + ((size_t)s3 << 9));
#pragma unroll
            for (int t = 0; t < 8; ++t) a[t] += bf2f(v0[t]);
#pragma unroll
            for (int t = 0; t < 8; ++t) a[t] += bf2f(v1[t]);
#pragma unroll
            for (int t = 0; t < 8; ++t) a[t] += bf2f(v2[t]);
#pragma unroll
            for (int t = 0; t < 8; ++t) a[t] += bf2f(v3[t]);
        }
        for (; j < rem; j += 2) {
            int jj = j + half;
            int s = __shfl(idx, (jj < rem) ? jj : j);
            if (jj < rem) {
                us8 v = *(const us8*)(hb + ((size_t)s << 9));
#pragma unroll
                for (int t = 0; t < 8; ++t) a[t] += bf2f(v[t]);
            }
        }
    }

#pragma unroll
    for (int t = 0; t < 8; ++t) a[t] += __shfl_xor(a[t], 32);

    if (half == 0) {
        float di = deg_inv[node];
        us8 o;
#pragma unroll
        for (int t = 0; t < 8; ++t) o[t] = f2bf(a[t] * di);
        *(us8*)(aggdst + (size_t)node * 512 + foff) = o;
    }
}

// ---------- fused GEMM: out = ELU( Acat(M x 512) @ Bcat^T (256 x 512) + bias ) ----------
// NO LDS, NO BARRIERS. Each wave loads its MFMA A/B fragments directly from global
// (per-wave: 16 rows x 64B contiguous per load instruction = fully coalesced), with a
// 2-deep register pipeline. 4 waves/block: wave (wy,wx) owns 64x64 of the 128x128 tile.
// A duplication across wx-waves and B duplication across wy-waves hit L1 (8KB/step).
// Acat workspace is padded to mtiles*128 rows so no row clamping is needed.
__global__ __launch_bounds__(NTHREADS) void gemm_kernel(
    const unsigned short* __restrict__ Acat, const unsigned short* __restrict__ Bcat,
    const float* __restrict__ bias,
    unsigned short* __restrict__ outb, float* __restrict__ outf, int M)
{
    const int lane = threadIdx.x & 63;
    const int wave = threadIdx.x >> 6;
    const int m0 = blockIdx.x * 128;
    const int j0 = blockIdx.y * 128;      // 2 n-tiles over N=256

    const int wy = wave >> 1;
    const int wx = wave & 1;
    const int lrow = lane & 15;
    const int khi = lane >> 4;            // 0..3 -> k sub-offset khi*8

    // per-lane fragment base pointers (fragment: lane holds [row=base+lrow][k + khi*8 + 0..7])
    const unsigned short* ap = Acat + (size_t)(m0 + wy * 64 + lrow) * 512 + khi * 8;
    const unsigned short* bp = Bcat + (size_t)(j0 + wx * 64 + lrow) * 512 + khi * 8;

    f32x4 acc[4][4] = {};
    bf16x8 a0[4], b0[4], a1[4], b1[4];

#define LOADSET(as_, bs_, t)                                                        \
    do {                                                                            \
        _Pragma("unroll")                                                           \
        for (int i = 0; i < 4; ++i)                                                 \
            as_[i] = *(const bf16x8*)(ap + (size_t)i * 16 * 512 + (t) * 32);        \
        _Pragma("unroll")                                                           \
        for (int i = 0; i < 4; ++i)                                                 \
            bs_[i] = *(const bf16x8*)(bp + (size_t)i * 16 * 512 + (t) * 32);        \
    } while (0)

#define MFMASET(as_, bs_)                                                           \
    do {                                                                            \
        _Pragma("unroll")                                                           \
        for (int i = 0; i < 4; ++i)                                                 \
            _Pragma("unroll")                                                       \
            for (int j = 0; j < 4; ++j)                                             \
                acc[i][j] = __builtin_amdgcn_mfma_f32_16x16x32_bf16(                \
                    as_[i], bs_[j], acc[i][j], 0, 0, 0);                            \
    } while (0)

    LOADSET(a0, b0, 0);
    for (int t = 0; t < 16; t += 2) {
        if (t + 1 < 16) LOADSET(a1, b1, t + 1);
        MFMASET(a0, b0);
        if (t + 2 < 16) LOADSET(a0, b0, t + 2);
        MFMASET(a1, b1);
    }
#undef LOADSET
#undef MFMASET

    // epilogue; D layout: col = lane&15, row = (lane>>4)*4 + reg
    const int rgrp = (lane >> 4) * 4;
    const bool fin = (outf != nullptr);
#pragma unroll
    for (int jj = 0; jj < 4; ++jj) {
        int n = j0 + wx * 64 + jj * 16 + lrow;
        float bn = bias[n];
#pragma unroll
        for (int i2 = 0; i2 < 4; ++i2) {
#pragma unroll
            for (int reg = 0; reg < 4; ++reg) {
                int m = m0 + wy * 64 + i2 * 16 + rgrp + reg;
                float v = acc[i2][jj][reg] + bn;
                v = (v > 0.f) ? v : expm1f(v);
                if (fin) {
                    if (m < M) outf[(size_t)m * H + n] = v;
                } else {
                    // padded workspace rows: unconditional write is in-bounds
                    outb[(size_t)m * 512 + H + n] = f2bf(v);
                }
            }
        }
    }
}

extern "C" void kernel_launch(void* const* d_in, const int* in_sizes, int n_in,
                              void* d_out, int out_size, void* d_ws, size_t ws_size,
                              hipStream_t stream) {
    const float* x = (const float*)d_in[0];
    const int* ei = (const int*)d_in[1];
    const float* W[6] = { (const float*)d_in[2], (const float*)d_in[3],
                          (const float*)d_in[4], (const float*)d_in[5],
                          (const float*)d_in[6], (const float*)d_in[7] };
    const float* bl[3] = { (const float*)d_in[8], (const float*)d_in[9],
                           (const float*)d_in[10] };
    float* out = (float*)d_out;

    const int N = in_sizes[0] / H;      // 50000
    const int E = in_sizes[1] / 2;      // 800000
    const int* src = ei;
    const int* dst = ei + E;
    const int mtiles = (N + 127) / 128; // 391

    // workspace carve (256B aligned)
    char* p = (char*)d_ws;
    auto carve = [&](size_t bytes) {
        char* q = p;
        p += (bytes + 255) & ~(size_t)255;
        return q;
    };
    int*            cnt      = (int*)carve((size_t)N * 4);
    int*            row_ptr  = (int*)carve((size_t)(N + 1) * 4);
    int*            cursor   = (int*)carve((size_t)N * 4);
    float*          deg_inv  = (float*)carve((size_t)N * 4);
    int*            csr_src  = (int*)carve((size_t)E * 4);
    int*            blocksum = (int*)carve((size_t)NTHREADS * 4);
    int*            blockoff = (int*)carve((size_t)NTHREADS * 4);
    unsigned short* Bcat     = (unsigned short*)carve((size_t)3 * H * 512 * 2);
    unsigned short* A0       = (unsigned short*)carve((size_t)mtiles * 128 * 512 * 2);
    unsigned short* A1       = (unsigned short*)carve((size_t)mtiles * 128 * 512 * 2);

    hipMemsetAsync(cnt, 0, (size_t)N * 4, stream);

    int n4 = N * H / 4;
    cast_x_kernel<<<(n4 + NTHREADS - 1) / NTHREADS, NTHREADS, 0, stream>>>(x, A0, n4);
    cast_w_kernel<<<(3 * H * 512) / NTHREADS, NTHREADS, 0, stream>>>(
        W[0], W[1], W[2], W[3], W[4], W[5], Bcat);

    hist_kernel<<<(E + NTHREADS - 1) / NTHREADS, NTHREADS, 0, stream>>>(dst, cnt, E);

    int nb = (N + NTHREADS - 1) / NTHREADS;   // 196 <= 256
    scan_partial_kernel<<<nb, NTHREADS, 0, stream>>>(cnt, row_ptr, blocksum, N);
    scan_sums_kernel<<<1, NTHREADS, 0, stream>>>(blocksum, blockoff, row_ptr, nb, N);
    scan_finish_kernel<<<nb, NTHREADS, 0, stream>>>(cnt, row_ptr, cursor, deg_inv, blockoff, N);

    fill_kernel<<<(E + NTHREADS - 1) / NTHREADS, NTHREADS, 0, stream>>>(src, dst, cursor, csr_src, E);

    unsigned short* cur = A0;
    unsigned short* nxt = A1;
    for (int l = 0; l < 3; ++l) {
        agg_kernel<<<(N + 3) / 4, NTHREADS, 0, stream>>>(
            cur + H, cur, row_ptr, csr_src, deg_inv, N);
        gemm_kernel<<<dim3(mtiles, 2), NTHREADS, 0, stream>>>(
            cur, Bcat + (size_t)l * H * 512, bl[l],
            nxt, (l == 2) ? out : nullptr, N);
        unsigned short* t = cur; cur = nxt; nxt = t;
    }
}

// Round 7
// 620.626 us; speedup vs baseline: 1.0080x; 1.0080x over previous
//
#include <hip/hip_runtime.h>
#include <hip/hip_bf16.h>

#define H 256
#define NTHREADS 256

// ---------- helpers ----------
static __device__ __forceinline__ float bf2f(unsigned short u) {
    return __uint_as_float(((unsigned int)u) << 16);
}
static __device__ __forceinline__ unsigned short f2bf(float f) {
    unsigned int x = __float_as_uint(f);
    unsigned int r = (x + 0x7fffu + ((x >> 16) & 1u)) >> 16;
    return (unsigned short)r;
}

typedef unsigned short us8 __attribute__((ext_vector_type(8)));
typedef __bf16 bf16x8 __attribute__((ext_vector_type(8)));
typedef float f32x4 __attribute__((ext_vector_type(4)));

// ---------- cast x (f32 -> bf16) into right half of Acat[m][512] ----------
__global__ __launch_bounds__(NTHREADS) void cast_x_kernel(
    const float* __restrict__ x, unsigned short* __restrict__ A, int n4)
{
    int i = blockIdx.x * NTHREADS + threadIdx.x;
    if (i < n4) {
        float4 v = ((const float4*)x)[i];
        ushort4 o;
        o.x = f2bf(v.x); o.y = f2bf(v.y); o.z = f2bf(v.z); o.w = f2bf(v.w);
        int m = i >> 6;          // 64 float4 per 256-col row
        int c = i & 63;
        ((ushort4*)(A + (size_t)m * 512 + H))[c] = o;
    }
}

// ---------- build Bcat[l][n][k] for all 3 layers in one launch ----------
// n in [0,256), k in [0,512): k<256 -> Wl[n][k], else Wr[n][k-256]
__global__ __launch_bounds__(NTHREADS) void cast_w_kernel(
    const float* __restrict__ Wl1, const float* __restrict__ Wr1,
    const float* __restrict__ Wl2, const float* __restrict__ Wr2,
    const float* __restrict__ Wl3, const float* __restrict__ Wr3,
    unsigned short* __restrict__ Bcat)
{
    int i = blockIdx.x * NTHREADS + threadIdx.x;   // 3*256*512 elements
    int l = i >> 17;
    int r = i & 131071;
    int n = r >> 9;
    int k = r & 511;
    const float* Wl = (l == 0) ? Wl1 : (l == 1) ? Wl2 : Wl3;
    const float* Wr = (l == 0) ? Wr1 : (l == 1) ? Wr2 : Wr3;
    float v = (k < H) ? Wl[n * H + k] : Wr[n * H + (k - H)];
    Bcat[i] = f2bf(v);
}

// ---------- degree histogram ----------
__global__ __launch_bounds__(NTHREADS) void hist_kernel(
    const int* __restrict__ dst, int* __restrict__ cnt, int E)
{
    int i = blockIdx.x * NTHREADS + threadIdx.x;
    if (i < E) atomicAdd(&cnt[dst[i]], 1);
}

// ---------- multi-block exclusive scan, stage 1 ----------
__global__ __launch_bounds__(NTHREADS) void scan_partial_kernel(
    const int* __restrict__ cnt, int* __restrict__ row_ptr,
    int* __restrict__ blocksum, int n_nodes)
{
    __shared__ int tmp[NTHREADS];
    int t = threadIdx.x;
    int i = blockIdx.x * NTHREADS + t;
    int v = (i < n_nodes) ? cnt[i] : 0;
    tmp[t] = v;
    __syncthreads();
#pragma unroll
    for (int d = 1; d < NTHREADS; d <<= 1) {
        int add = (t >= d) ? tmp[t - d] : 0;
        __syncthreads();
        tmp[t] += add;
        __syncthreads();
    }
    if (i < n_nodes) row_ptr[i] = tmp[t] - v;   // exclusive
    if (t == NTHREADS - 1) blocksum[blockIdx.x] = tmp[t];
}

// ---------- stage 2 ----------
__global__ __launch_bounds__(NTHREADS) void scan_sums_kernel(
    int* __restrict__ blocksum, int* __restrict__ blockoff,
    int* __restrict__ row_ptr, int n_blocks, int n_nodes)
{
    __shared__ int tmp[NTHREADS];
    int t = threadIdx.x;
    int v = (t < n_blocks) ? blocksum[t] : 0;
    tmp[t] = v;
    __syncthreads();
#pragma unroll
    for (int d = 1; d < NTHREADS; d <<= 1) {
        int add = (t >= d) ? tmp[t - d] : 0;
        __syncthreads();
        tmp[t] += add;
        __syncthreads();
    }
    if (t < n_blocks) blockoff[t] = tmp[t] - v;
    if (t == NTHREADS - 1) row_ptr[n_nodes] = tmp[t];
}

// ---------- stage 3 ----------
__global__ __launch_bounds__(NTHREADS) void scan_finish_kernel(
    const int* __restrict__ cnt, int* __restrict__ row_ptr,
    int* __restrict__ cursor, float* __restrict__ deg_inv,
    const int* __restrict__ blockoff, int n_nodes)
{
    int i = blockIdx.x * NTHREADS + threadIdx.x;
    if (i < n_nodes) {
        int r = row_ptr[i] + blockoff[blockIdx.x];
        row_ptr[i] = r;
        cursor[i] = r;
        deg_inv[i] = 1.0f / (float)max(cnt[i], 1);
    }
}

// ---------- scatter edges into CSR order ----------
__global__ __launch_bounds__(NTHREADS) void fill_kernel(
    const int* __restrict__ src, const int* __restrict__ dst,
    int* __restrict__ cursor, int* __restrict__ csr_src, int E)
{
    int i = blockIdx.x * NTHREADS + threadIdx.x;
    if (i < E) {
        int p = atomicAdd(&cursor[dst[i]], 1);
        csr_src[p] = src[i];
    }
}

// ---------- mean-aggregate: gather h rows (right half of Acat) -> agg (left half) ----------
// One wave per node. Lanes 0-31 even edges, 32-63 odd edges; 8 feats (16B) per lane.
__global__ __launch_bounds__(NTHREADS) void agg_kernel(
    const unsigned short* __restrict__ hsrc,   // Acat + 256 (h base), row stride 512
    unsigned short* __restrict__ aggdst,       // Acat (agg base), row stride 512
    const int* __restrict__ row_ptr, const int* __restrict__ csr_src,
    const float* __restrict__ deg_inv, int n_nodes)
{
    int wave = threadIdx.x >> 6;
    int lane = threadIdx.x & 63;
    int node = blockIdx.x * 4 + wave;
    if (node >= n_nodes) return;
    int beg = row_ptr[node];
    int cnt = row_ptr[node + 1] - beg;
    const int half = lane >> 5;
    const int foff = (lane & 31) * 8;
    const unsigned short* hb = hsrc + foff;

    float a[8] = {0.f, 0.f, 0.f, 0.f, 0.f, 0.f, 0.f, 0.f};

    for (int e = 0; e < cnt; e += 64) {
        int rem = min(64, cnt - e);
        int idx = (lane < rem) ? csr_src[beg + e + lane] : 0;
        int j = 0;
        for (; j + 16 <= rem; j += 16) {
            int s0 = __shfl(idx, j + 0 + half);
            int s1 = __shfl(idx, j + 2 + half);
            int s2 = __shfl(idx, j + 4 + half);
            int s3 = __shfl(idx, j + 6 + half);
            int s4 = __shfl(idx, j + 8 + half);
            int s5 = __shfl(idx, j + 10 + half);
            int s6 = __shfl(idx, j + 12 + half);
            int s7 = __shfl(idx, j + 14 + half);
            us8 v0 = *(const us8*)(hb + ((size_t)s0 << 9));
            us8 v1 = *(const us8*)(hb + ((size_t)s1 << 9));
            us8 v2 = *(const us8*)(hb + ((size_t)s2 << 9));
            us8 v3 = *(const us8*)(hb + ((size_t)s3 << 9));
            us8 v4 = *(const us8*)(hb + ((size_t)s4 << 9));
            us8 v5 = *(const us8*)(hb + ((size_t)s5 << 9));
            us8 v6 = *(const us8*)(hb + ((size_t)s6 << 9));
            us8 v7 = *(const us8*)(hb + ((size_t)s7 << 9));
#pragma unroll
            for (int t = 0; t < 8; ++t) a[t] += bf2f(v0[t]);
#pragma unroll
            for (int t = 0; t < 8; ++t) a[t] += bf2f(v1[t]);
#pragma unroll
            for (int t = 0; t < 8; ++t) a[t] += bf2f(v2[t]);
#pragma unroll
            for (int t = 0; t < 8; ++t) a[t] += bf2f(v3[t]);
#pragma unroll
            for (int t = 0; t < 8; ++t) a[t] += bf2f(v4[t]);
#pragma unroll
            for (int t = 0; t < 8; ++t) a[t] += bf2f(v5[t]);
#pragma unroll
            for (int t = 0; t < 8; ++t) a[t] += bf2f(v6[t]);
#pragma unroll
            for (int t = 0; t < 8; ++t) a[t] += bf2f(v7[t]);
        }
        for (; j + 8 <= rem; j += 8) {
            int s0 = __shfl(idx, j + 0 + half);
            int s1 = __shfl(idx, j + 2 + half);
            int s2 = __shfl(idx, j + 4 + half);
            int s3 = __shfl(idx, j + 6 + half);
            us8 v0 = *(const us8*)(hb + ((size_t)s0 << 9));
            us8 v1 = *(const us8*)(hb + ((size_t)s1 << 9));
            us8 v2 = *(const us8*)(hb + ((size_t)s2 << 9));
            us8 v3 = *(const us8*)(hb + ((size_t)s3 << 9));
#pragma unroll
            for (int t = 0; t < 8; ++t) a[t] += bf2f(v0[t]);
#pragma unroll
            for (int t = 0; t < 8; ++t) a[t] += bf2f(v1[t]);
#pragma unroll
            for (int t = 0; t < 8; ++t) a[t] += bf2f(v2[t]);
#pragma unroll
            for (int t = 0; t < 8; ++t) a[t] += bf2f(v3[t]);
        }
        for (; j < rem; j += 2) {
            int jj = j + half;
            int s = __shfl(idx, (jj < rem) ? jj : j);
            if (jj < rem) {
                us8 v = *(const us8*)(hb + ((size_t)s << 9));
#pragma unroll
                for (int t = 0; t < 8; ++t) a[t] += bf2f(v[t]);
            }
        }
    }

#pragma unroll
    for (int t = 0; t < 8; ++t) a[t] += __shfl_xor(a[t], 32);

    if (half == 0) {
        float di = deg_inv[node];
        us8 o;
#pragma unroll
        for (int t = 0; t < 8; ++t) o[t] = f2bf(a[t] * di);
        *(us8*)(aggdst + (size_t)node * 512 + foff) = o;
    }
}

// ---------- fused GEMM: out = ELU( Acat(M x 512) @ Bcat^T (256 x 512) + bias ) ----------
// NO LDS, NO BARRIERS. Each wave loads its MFMA A/B fragments directly from global
// (16 rows x 64B contiguous per fragment load = fully coalesced), 2-deep register
// pipeline. __launch_bounds__(256,2) -> 256-VGPR budget so acc (64) + two fragment
// sets (2x64) live in registers (round-6 failure: default bounds capped at 68 VGPR
// and spilled the pipeline to scratch: WRITE_SIZE +24MB, MfmaUtil 5%).
__global__ __launch_bounds__(NTHREADS, 2) void gemm_kernel(
    const unsigned short* __restrict__ Acat, const unsigned short* __restrict__ Bcat,
    const float* __restrict__ bias,
    unsigned short* __restrict__ outb, float* __restrict__ outf, int M)
{
    const int lane = threadIdx.x & 63;
    const int wave = threadIdx.x >> 6;
    const int m0 = blockIdx.x * 128;
    const int j0 = blockIdx.y * 128;      // 2 n-tiles over N=256

    const int wy = wave >> 1;
    const int wx = wave & 1;
    const int lrow = lane & 15;
    const int khi = lane >> 4;            // 0..3 -> k sub-offset khi*8

    // per-lane fragment base pointers (fragment: lane holds [row=base+lrow][k + khi*8 + 0..7])
    const unsigned short* ap = Acat + (size_t)(m0 + wy * 64 + lrow) * 512 + khi * 8;
    const unsigned short* bp = Bcat + (size_t)(j0 + wx * 64 + lrow) * 512 + khi * 8;

    f32x4 acc[4][4] = {};
    bf16x8 a0[4], b0[4], a1[4], b1[4];

#define LOADSET(as_, bs_, t)                                                        \
    do {                                                                            \
        _Pragma("unroll")                                                           \
        for (int i = 0; i < 4; ++i)                                                 \
            as_[i] = *(const bf16x8*)(ap + (size_t)i * 16 * 512 + (t) * 32);        \
        _Pragma("unroll")                                                           \
        for (int i = 0; i < 4; ++i)                                                 \
            bs_[i] = *(const bf16x8*)(bp + (size_t)i * 16 * 512 + (t) * 32);        \
    } while (0)

#define MFMASET(as_, bs_)                                                           \
    do {                                                                            \
        _Pragma("unroll")                                                           \
        for (int i = 0; i < 4; ++i)                                                 \
            _Pragma("unroll")                                                       \
            for (int j = 0; j < 4; ++j)                                             \
                acc[i][j] = __builtin_amdgcn_mfma_f32_16x16x32_bf16(                \
                    as_[i], bs_[j], acc[i][j], 0, 0, 0);                            \
    } while (0)

    LOADSET(a0, b0, 0);
    for (int t = 0; t < 16; t += 2) {
        if (t + 1 < 16) LOADSET(a1, b1, t + 1);
        MFMASET(a0, b0);
        if (t + 2 < 16) LOADSET(a0, b0, t + 2);
        MFMASET(a1, b1);
    }
#undef LOADSET
#undef MFMASET

    // epilogue; D layout: col = lane&15, row = (lane>>4)*4 + reg
    const int rgrp = (lane >> 4) * 4;
    const bool fin = (outf != nullptr);
#pragma unroll
    for (int jj = 0; jj < 4; ++jj) {
        int n = j0 + wx * 64 + jj * 16 + lrow;
        float bn = bias[n];
#pragma unroll
        for (int i2 = 0; i2 < 4; ++i2) {
#pragma unroll
            for (int reg = 0; reg < 4; ++reg) {
                int m = m0 + wy * 64 + i2 * 16 + rgrp + reg;
                float v = acc[i2][jj][reg] + bn;
                v = (v > 0.f) ? v : expm1f(v);
                if (fin) {
                    if (m < M) outf[(size_t)m * H + n] = v;
                } else {
                    // padded workspace rows: unconditional write is in-bounds
                    outb[(size_t)m * 512 + H + n] = f2bf(v);
                }
            }
        }
    }
}

extern "C" void kernel_launch(void* const* d_in, const int* in_sizes, int n_in,
                              void* d_out, int out_size, void* d_ws, size_t ws_size,
                              hipStream_t stream) {
    const float* x = (const float*)d_in[0];
    const int* ei = (const int*)d_in[1];
    const float* W[6] = { (const float*)d_in[2], (const float*)d_in[3],
                          (const float*)d_in[4], (const float*)d_in[5],
                          (const float*)d_in[6], (const float*)d_in[7] };
    const float* bl[3] = { (const float*)d_in[8], (const float*)d_in[9],
                           (const float*)d_in[10] };
    float* out = (float*)d_out;

    const int N = in_sizes[0] / H;      // 50000
    const int E = in_sizes[1] / 2;      // 800000
    const int* src = ei;
    const int* dst = ei + E;
    const int mtiles = (N + 127) / 128; // 391

    // workspace carve (256B aligned)
    char* p = (char*)d_ws;
    auto carve = [&](size_t bytes) {
        char* q = p;
        p += (bytes + 255) & ~(size_t)255;
        return q;
    };
    int*            cnt      = (int*)carve((size_t)N * 4);
    int*            row_ptr  = (int*)carve((size_t)(N + 1) * 4);
    int*            cursor   = (int*)carve((size_t)N * 4);
    float*          deg_inv  = (float*)carve((size_t)N * 4);
    int*            csr_src  = (int*)carve((size_t)E * 4);
    int*            blocksum = (int*)carve((size_t)NTHREADS * 4);
    int*            blockoff = (int*)carve((size_t)NTHREADS * 4);
    unsigned short* Bcat     = (unsigned short*)carve((size_t)3 * H * 512 * 2);
    unsigned short* A0       = (unsigned short*)carve((size_t)mtiles * 128 * 512 * 2);
    unsigned short* A1       = (unsigned short*)carve((size_t)mtiles * 128 * 512 * 2);

    hipMemsetAsync(cnt, 0, (size_t)N * 4, stream);

    int n4 = N * H / 4;
    cast_x_kernel<<<(n4 + NTHREADS - 1) / NTHREADS, NTHREADS, 0, stream>>>(x, A0, n4);
    cast_w_kernel<<<(3 * H * 512) / NTHREADS, NTHREADS, 0, stream>>>(
        W[0], W[1], W[2], W[3], W[4], W[5], Bcat);

    hist_kernel<<<(E + NTHREADS - 1) / NTHREADS, NTHREADS, 0, stream>>>(dst, cnt, E);

    int nb = (N + NTHREADS - 1) / NTHREADS;   // 196 <= 256
    scan_partial_kernel<<<nb, NTHREADS, 0, stream>>>(cnt, row_ptr, blocksum, N);
    scan_sums_kernel<<<1, NTHREADS, 0, stream>>>(blocksum, blockoff, row_ptr, nb, N);
    scan_finish_kernel<<<nb, NTHREADS, 0, stream>>>(cnt, row_ptr, cursor, deg_inv, blockoff, N);

    fill_kernel<<<(E + NTHREADS - 1) / NTHREADS, NTHREADS, 0, stream>>>(src, dst, cursor, csr_src, E);

    unsigned short* cur = A0;
    unsigned short* nxt = A1;
    for (int l = 0; l < 3; ++l) {
        agg_kernel<<<(N + 3) / 4, NTHREADS, 0, stream>>>(
            cur + H, cur, row_ptr, csr_src, deg_inv, N);
        gemm_kernel<<<dim3(mtiles, 2), NTHREADS, 0, stream>>>(
            cur, Bcat + (size_t)l * H * 512, bl[l],
            nxt, (l == 2) ? out : nullptr, N);
        unsigned short* t = cur; cur = nxt; nxt = t;
    }
}

// Round 8
// 500.918 us; speedup vs baseline: 1.2489x; 1.2390x over previous
//
#include <hip/hip_runtime.h>
#include <hip/hip_bf16.h>

#define H 256
#define NTHREADS 256

// ---------- helpers ----------
static __device__ __forceinline__ float bf2f(unsigned short u) {
    return __uint_as_float(((unsigned int)u) << 16);
}
static __device__ __forceinline__ unsigned short f2bf(float f) {
    unsigned int x = __float_as_uint(f);
    unsigned int r = (x + 0x7fffu + ((x >> 16) & 1u)) >> 16;
    return (unsigned short)r;
}

typedef unsigned short us8 __attribute__((ext_vector_type(8)));
typedef __bf16 bf16x8 __attribute__((ext_vector_type(8)));
typedef float f32x4 __attribute__((ext_vector_type(4)));

// ---------- cast x (f32 -> bf16) into right half of Acat[m][512] ----------
__global__ __launch_bounds__(NTHREADS) void cast_x_kernel(
    const float* __restrict__ x, unsigned short* __restrict__ A, int n4)
{
    int i = blockIdx.x * NTHREADS + threadIdx.x;
    if (i < n4) {
        float4 v = ((const float4*)x)[i];
        ushort4 o;
        o.x = f2bf(v.x); o.y = f2bf(v.y); o.z = f2bf(v.z); o.w = f2bf(v.w);
        int m = i >> 6;          // 64 float4 per 256-col row
        int c = i & 63;
        ((ushort4*)(A + (size_t)m * 512 + H))[c] = o;
    }
}

// ---------- build Bcat[l][n][k] for all 3 layers in one launch ----------
// n in [0,256), k in [0,512): k<256 -> Wl[n][k], else Wr[n][k-256]
__global__ __launch_bounds__(NTHREADS) void cast_w_kernel(
    const float* __restrict__ Wl1, const float* __restrict__ Wr1,
    const float* __restrict__ Wl2, const float* __restrict__ Wr2,
    const float* __restrict__ Wl3, const float* __restrict__ Wr3,
    unsigned short* __restrict__ Bcat)
{
    int i = blockIdx.x * NTHREADS + threadIdx.x;   // 3*256*512 elements
    int l = i >> 17;
    int r = i & 131071;
    int n = r >> 9;
    int k = r & 511;
    const float* Wl = (l == 0) ? Wl1 : (l == 1) ? Wl2 : Wl3;
    const float* Wr = (l == 0) ? Wr1 : (l == 1) ? Wr2 : Wr3;
    float v = (k < H) ? Wl[n * H + k] : Wr[n * H + (k - H)];
    Bcat[i] = f2bf(v);
}

// ---------- degree histogram ----------
__global__ __launch_bounds__(NTHREADS) void hist_kernel(
    const int* __restrict__ dst, int* __restrict__ cnt, int E)
{
    int i = blockIdx.x * NTHREADS + threadIdx.x;
    if (i < E) atomicAdd(&cnt[dst[i]], 1);
}

// ---------- multi-block exclusive scan, stage 1 ----------
__global__ __launch_bounds__(NTHREADS) void scan_partial_kernel(
    const int* __restrict__ cnt, int* __restrict__ row_ptr,
    int* __restrict__ blocksum, int n_nodes)
{
    __shared__ int tmp[NTHREADS];
    int t = threadIdx.x;
    int i = blockIdx.x * NTHREADS + t;
    int v = (i < n_nodes) ? cnt[i] : 0;
    tmp[t] = v;
    __syncthreads();
#pragma unroll
    for (int d = 1; d < NTHREADS; d <<= 1) {
        int add = (t >= d) ? tmp[t - d] : 0;
        __syncthreads();
        tmp[t] += add;
        __syncthreads();
    }
    if (i < n_nodes) row_ptr[i] = tmp[t] - v;   // exclusive
    if (t == NTHREADS - 1) blocksum[blockIdx.x] = tmp[t];
}

// ---------- stage 2 ----------
__global__ __launch_bounds__(NTHREADS) void scan_sums_kernel(
    int* __restrict__ blocksum, int* __restrict__ blockoff,
    int* __restrict__ row_ptr, int n_blocks, int n_nodes)
{
    __shared__ int tmp[NTHREADS];
    int t = threadIdx.x;
    int v = (t < n_blocks) ? blocksum[t] : 0;
    tmp[t] = v;
    __syncthreads();
#pragma unroll
    for (int d = 1; d < NTHREADS; d <<= 1) {
        int add = (t >= d) ? tmp[t - d] : 0;
        __syncthreads();
        tmp[t] += add;
        __syncthreads();
    }
    if (t < n_blocks) blockoff[t] = tmp[t] - v;
    if (t == NTHREADS - 1) row_ptr[n_nodes] = tmp[t];
}

// ---------- stage 3 ----------
__global__ __launch_bounds__(NTHREADS) void scan_finish_kernel(
    const int* __restrict__ cnt, int* __restrict__ row_ptr,
    int* __restrict__ cursor, float* __restrict__ deg_inv,
    const int* __restrict__ blockoff, int n_nodes)
{
    int i = blockIdx.x * NTHREADS + threadIdx.x;
    if (i < n_nodes) {
        int r = row_ptr[i] + blockoff[blockIdx.x];
        row_ptr[i] = r;
        cursor[i] = r;
        deg_inv[i] = 1.0f / (float)max(cnt[i], 1);
    }
}

// ---------- scatter edges into CSR order ----------
__global__ __launch_bounds__(NTHREADS) void fill_kernel(
    const int* __restrict__ src, const int* __restrict__ dst,
    int* __restrict__ cursor, int* __restrict__ csr_src, int E)
{
    int i = blockIdx.x * NTHREADS + threadIdx.x;
    if (i < E) {
        int p = atomicAdd(&cursor[dst[i]], 1);
        csr_src[p] = src[i];
    }
}

// ---------- mean-aggregate: gather h rows (right half of Acat) -> agg (left half) ----------
// One wave per node. Lanes 0-31 even edges, 32-63 odd edges; 8 feats (16B) per lane.
__global__ __launch_bounds__(NTHREADS) void agg_kernel(
    const unsigned short* __restrict__ hsrc,   // Acat + 256 (h base), row stride 512
    unsigned short* __restrict__ aggdst,       // Acat (agg base), row stride 512
    const int* __restrict__ row_ptr, const int* __restrict__ csr_src,
    const float* __restrict__ deg_inv, int n_nodes)
{
    int wave = threadIdx.x >> 6;
    int lane = threadIdx.x & 63;
    int node = blockIdx.x * 4 + wave;
    if (node >= n_nodes) return;
    int beg = row_ptr[node];
    int cnt = row_ptr[node + 1] - beg;
    const int half = lane >> 5;
    const int foff = (lane & 31) * 8;
    const unsigned short* hb = hsrc + foff;

    float a[8] = {0.f, 0.f, 0.f, 0.f, 0.f, 0.f, 0.f, 0.f};

    for (int e = 0; e < cnt; e += 64) {
        int rem = min(64, cnt - e);
        int idx = (lane < rem) ? csr_src[beg + e + lane] : 0;
        int j = 0;
        for (; j + 16 <= rem; j += 16) {
            int s0 = __shfl(idx, j + 0 + half);
            int s1 = __shfl(idx, j + 2 + half);
            int s2 = __shfl(idx, j + 4 + half);
            int s3 = __shfl(idx, j + 6 + half);
            int s4 = __shfl(idx, j + 8 + half);
            int s5 = __shfl(idx, j + 10 + half);
            int s6 = __shfl(idx, j + 12 + half);
            int s7 = __shfl(idx, j + 14 + half);
            us8 v0 = *(const us8*)(hb + ((size_t)s0 << 9));
            us8 v1 = *(const us8*)(hb + ((size_t)s1 << 9));
            us8 v2 = *(const us8*)(hb + ((size_t)s2 << 9));
            us8 v3 = *(const us8*)(hb + ((size_t)s3 << 9));
            us8 v4 = *(const us8*)(hb + ((size_t)s4 << 9));
            us8 v5 = *(const us8*)(hb + ((size_t)s5 << 9));
            us8 v6 = *(const us8*)(hb + ((size_t)s6 << 9));
            us8 v7 = *(const us8*)(hb + ((size_t)s7 << 9));
#pragma unroll
            for (int t = 0; t < 8; ++t) a[t] += bf2f(v0[t]);
#pragma unroll
            for (int t = 0; t < 8; ++t) a[t] += bf2f(v1[t]);
#pragma unroll
            for (int t = 0; t < 8; ++t) a[t] += bf2f(v2[t]);
#pragma unroll
            for (int t = 0; t < 8; ++t) a[t] += bf2f(v3[t]);
#pragma unroll
            for (int t = 0; t < 8; ++t) a[t] += bf2f(v4[t]);
#pragma unroll
            for (int t = 0; t < 8; ++t) a[t] += bf2f(v5[t]);
#pragma unroll
            for (int t = 0; t < 8; ++t) a[t] += bf2f(v6[t]);
#pragma unroll
            for (int t = 0; t < 8; ++t) a[t] += bf2f(v7[t]);
        }
        for (; j + 8 <= rem; j += 8) {
            int s0 = __shfl(idx, j + 0 + half);
            int s1 = __shfl(idx, j + 2 + half);
            int s2 = __shfl(idx, j + 4 + half);
            int s3 = __shfl(idx, j + 6 + half);
            us8 v0 = *(const us8*)(hb + ((size_t)s0 << 9));
            us8 v1 = *(const us8*)(hb + ((size_t)s1 << 9));
            us8 v2 = *(const us8*)(hb + ((size_t)s2 << 9));
            us8 v3 = *(const us8*)(hb + ((size_t)s3 << 9));
#pragma unroll
            for (int t = 0; t < 8; ++t) a[t] += bf2f(v0[t]);
#pragma unroll
            for (int t = 0; t < 8; ++t) a[t] += bf2f(v1[t]);
#pragma unroll
            for (int t = 0; t < 8; ++t) a[t] += bf2f(v2[t]);
#pragma unroll
            for (int t = 0; t < 8; ++t) a[t] += bf2f(v3[t]);
        }
        for (; j < rem; j += 2) {
            int jj = j + half;
            int s = __shfl(idx, (jj < rem) ? jj : j);
            if (jj < rem) {
                us8 v = *(const us8*)(hb + ((size_t)s << 9));
#pragma unroll
                for (int t = 0; t < 8; ++t) a[t] += bf2f(v[t]);
            }
        }
    }

#pragma unroll
    for (int t = 0; t < 8; ++t) a[t] += __shfl_xor(a[t], 32);

    if (half == 0) {
        float di = deg_inv[node];
        us8 o;
#pragma unroll
        for (int t = 0; t < 8; ++t) o[t] = f2bf(a[t] * di);
        *(us8*)(aggdst + (size_t)node * 512 + foff) = o;
    }
}

// ---------- fused GEMM: out = ELU( Acat(M x 512) @ Bcat^T (256 x 512) + bias ) ----------
// Triple-buffered LDS (BK=32, 3x16KB=48KB -> 3 blocks/CU), COUNTED vmcnt + raw s_barrier:
// prefetch loads for tile t+1/t+2 stay in flight across the barrier (the __syncthreads
// version drains vmcnt(0) every K-step -- the invariant ~61us stall of rounds 2-4).
// Race-safety: buffer written at iter t was last read at iter t-3; every wave past the
// iter-t barrier has finished those reads. Loads are confined per-iteration by the
// memory-clobber asm waits.
__global__ __launch_bounds__(NTHREADS, 3) void gemm_kernel(
    const unsigned short* __restrict__ Acat, const unsigned short* __restrict__ Bcat,
    const float* __restrict__ bias,
    unsigned short* __restrict__ outb, float* __restrict__ outf, int M)
{
    __shared__ __align__(16) unsigned short As[3][4096];   // [buf][128 rows x 32 cols]
    __shared__ __align__(16) unsigned short Bs[3][4096];
    const int tid = threadIdx.x;
    const int lane = tid & 63;
    const int wave = tid >> 6;
    const int m0 = blockIdx.x * 128;
    const int j0 = blockIdx.y * 128;      // 2 n-tiles over N=256

    const int wy = wave >> 1;
    const int wx = wave & 1;
    const int lrow = lane & 15;
    const int kc = lane >> 4;             // 0..3 -> 16B chunk within 32-col tile row

    // stage: thread covers slots s0 (call 0) and s1 (call 1); slot s = (row<<2)|chunk'
    // with source chunk = chunk' ^ ((row>>1)&3)  (bank-spread swizzle, 2-way = free)
    const int s0 = wave * 64 + lane;
    const int s1 = 256 + s0;
    const int rA0 = s0 >> 2, cA0 = (s0 & 3) ^ ((s0 >> 3) & 3);
    const int rA1 = s1 >> 2, cA1 = (s1 & 3) ^ ((s1 >> 3) & 3);
    const unsigned short* gA0 = Acat + (size_t)(m0 + rA0) * 512 + cA0 * 8;
    const unsigned short* gA1 = Acat + (size_t)(m0 + rA1) * 512 + cA1 * 8;
    const unsigned short* gB0 = Bcat + (size_t)(j0 + rA0) * 512 + cA0 * 8;
    const unsigned short* gB1 = Bcat + (size_t)(j0 + rA1) * 512 + cA1 * 8;
    const int ldsoff0 = (wave * 64) * 8;          // ushort offset, call 0 (lane x16B implicit)
    const int ldsoff1 = (256 + wave * 64) * 8;    // call 1

    // frag read offsets (ushorts): row*32 + (kc ^ ((row>>1)&3))*8
    int offA[4], offB[4];
#pragma unroll
    for (int i = 0; i < 4; ++i) {
        int ra = wy * 64 + i * 16 + lrow;
        offA[i] = ra * 32 + ((kc ^ ((ra >> 1) & 3)) << 3);
        int rb = wx * 64 + i * 16 + lrow;
        offB[i] = rb * 32 + ((kc ^ ((rb >> 1) & 3)) << 3);
    }

#define STAGE(tt, buf) do {                                                         \
    const int k0_ = (tt) * 32;                                                      \
    __builtin_amdgcn_global_load_lds(                                               \
        (const __attribute__((address_space(1))) void*)(gA0 + k0_),                 \
        (__attribute__((address_space(3))) void*)(&As[buf][ldsoff0]), 16, 0, 0);    \
    __builtin_amdgcn_global_load_lds(                                               \
        (const __attribute__((address_space(1))) void*)(gA1 + k0_),                 \
        (__attribute__((address_space(3))) void*)(&As[buf][ldsoff1]), 16, 0, 0);    \
    __builtin_amdgcn_global_load_lds(                                               \
        (const __attribute__((address_space(1))) void*)(gB0 + k0_),                 \
        (__attribute__((address_space(3))) void*)(&Bs[buf][ldsoff0]), 16, 0, 0);    \
    __builtin_amdgcn_global_load_lds(                                               \
        (const __attribute__((address_space(1))) void*)(gB1 + k0_),                 \
        (__attribute__((address_space(3))) void*)(&Bs[buf][ldsoff1]), 16, 0, 0);    \
} while (0)

    f32x4 acc[4][4] = {};
    STAGE(0, 0);
    STAGE(1, 1);

    int cur = 0, stg = 2;
    for (int t = 0; t < 16; ++t) {
        // wait tile t's 4 loads only; tile t+1's stay in flight across the barrier
        if (t < 15) asm volatile("s_waitcnt vmcnt(4)" ::: "memory");
        else        asm volatile("s_waitcnt vmcnt(0)" ::: "memory");
        __builtin_amdgcn_s_barrier();
        const unsigned short* as = As[cur];
        const unsigned short* bs = Bs[cur];
        bf16x8 a[4], b[4];
#pragma unroll
        for (int i = 0; i < 4; ++i) a[i] = *(const bf16x8*)(as + offA[i]);
#pragma unroll
        for (int i = 0; i < 4; ++i) b[i] = *(const bf16x8*)(bs + offB[i]);
        if (t + 2 < 16) STAGE(t + 2, stg);
        __builtin_amdgcn_sched_barrier(0);
        __builtin_amdgcn_s_setprio(1);
#pragma unroll
        for (int i = 0; i < 4; ++i)
#pragma unroll
            for (int j = 0; j < 4; ++j)
                acc[i][j] = __builtin_amdgcn_mfma_f32_16x16x32_bf16(
                    a[i], b[j], acc[i][j], 0, 0, 0);
        __builtin_amdgcn_s_setprio(0);
        cur = (cur == 2) ? 0 : cur + 1;
        stg = (stg == 2) ? 0 : stg + 1;
    }
#undef STAGE

    // epilogue; D layout: col = lane&15, row = (lane>>4)*4 + reg
    const int rgrp = (lane >> 4) * 4;
    const bool fin = (outf != nullptr);
#pragma unroll
    for (int jj = 0; jj < 4; ++jj) {
        int n = j0 + wx * 64 + jj * 16 + lrow;
        float bn = bias[n];
#pragma unroll
        for (int i2 = 0; i2 < 4; ++i2) {
#pragma unroll
            for (int reg = 0; reg < 4; ++reg) {
                int m = m0 + wy * 64 + i2 * 16 + rgrp + reg;
                float v = acc[i2][jj][reg] + bn;
                v = (v > 0.f) ? v : expm1f(v);
                if (fin) {
                    if (m < M) outf[(size_t)m * H + n] = v;
                } else {
                    // padded workspace rows: unconditional write is in-bounds
                    outb[(size_t)m * 512 + H + n] = f2bf(v);
                }
            }
        }
    }
}

extern "C" void kernel_launch(void* const* d_in, const int* in_sizes, int n_in,
                              void* d_out, int out_size, void* d_ws, size_t ws_size,
                              hipStream_t stream) {
    const float* x = (const float*)d_in[0];
    const int* ei = (const int*)d_in[1];
    const float* W[6] = { (const float*)d_in[2], (const float*)d_in[3],
                          (const float*)d_in[4], (const float*)d_in[5],
                          (const float*)d_in[6], (const float*)d_in[7] };
    const float* bl[3] = { (const float*)d_in[8], (const float*)d_in[9],
                           (const float*)d_in[10] };
    float* out = (float*)d_out;

    const int N = in_sizes[0] / H;      // 50000
    const int E = in_sizes[1] / 2;      // 800000
    const int* src = ei;
    const int* dst = ei + E;
    const int mtiles = (N + 127) / 128; // 391

    // workspace carve (256B aligned)
    char* p = (char*)d_ws;
    auto carve = [&](size_t bytes) {
        char* q = p;
        p += (bytes + 255) & ~(size_t)255;
        return q;
    };
    int*            cnt      = (int*)carve((size_t)N * 4);
    int*            row_ptr  = (int*)carve((size_t)(N + 1) * 4);
    int*            cursor   = (int*)carve((size_t)N * 4);
    float*          deg_inv  = (float*)carve((size_t)N * 4);
    int*            csr_src  = (int*)carve((size_t)E * 4);
    int*            blocksum = (int*)carve((size_t)NTHREADS * 4);
    int*            blockoff = (int*)carve((size_t)NTHREADS * 4);
    unsigned short* Bcat     = (unsigned short*)carve((size_t)3 * H * 512 * 2);
    unsigned short* A0       = (unsigned short*)carve((size_t)mtiles * 128 * 512 * 2);
    unsigned short* A1       = (unsigned short*)carve((size_t)mtiles * 128 * 512 * 2);

    hipMemsetAsync(cnt, 0, (size_t)N * 4, stream);

    int n4 = N * H / 4;
    cast_x_kernel<<<(n4 + NTHREADS - 1) / NTHREADS, NTHREADS, 0, stream>>>(x, A0, n4);
    cast_w_kernel<<<(3 * H * 512) / NTHREADS, NTHREADS, 0, stream>>>(
        W[0], W[1], W[2], W[3], W[4], W[5], Bcat);

    hist_kernel<<<(E + NTHREADS - 1) / NTHREADS, NTHREADS, 0, stream>>>(dst, cnt, E);

    int nb = (N + NTHREADS - 1) / NTHREADS;   // 196 <= 256
    scan_partial_kernel<<<nb, NTHREADS, 0, stream>>>(cnt, row_ptr, blocksum, N);
    scan_sums_kernel<<<1, NTHREADS, 0, stream>>>(blocksum, blockoff, row_ptr, nb, N);
    scan_finish_kernel<<<nb, NTHREADS, 0, stream>>>(cnt, row_ptr, cursor, deg_inv, blockoff, N);

    fill_kernel<<<(E + NTHREADS - 1) / NTHREADS, NTHREADS, 0, stream>>>(src, dst, cursor, csr_src, E);

    unsigned short* cur = A0;
    unsigned short* nxt = A1;
    for (int l = 0; l < 3; ++l) {
        agg_kernel<<<(N + 3) / 4, NTHREADS, 0, stream>>>(
            cur + H, cur, row_ptr, csr_src, deg_inv, N);
        gemm_kernel<<<dim3(mtiles, 2), NTHREADS, 0, stream>>>(
            cur, Bcat + (size_t)l * H * 512, bl[l],
            nxt, (l == 2) ? out : nullptr, N);
        unsigned short* t = cur; cur = nxt; nxt = t;
    }
}